// Round 10
// baseline (179.847 us; speedup 1.0000x reference)
//
#include <hip/hip_runtime.h>

// Problem constants (match reference: B=16, S=4096, D=128)
#define BB   16
#define SS   4096
#define DD   128
#define NCH  512            // chunks per batch
#define TT   (SS / NCH)     // 8 steps per chunk
#define NWAVE (BB * NCH)    // 8192 chunks
#define KCH  8              // chunks per wave (LDS-pipelined)
#define P13_WPB 2           // waves per block in pass1/pass3
#define P13_NBLK (NWAVE / KCH / P13_WPB)   // 512 blocks

#define LN_EPS  1e-5f
#define REC_EPS 1e-8f

__device__ __forceinline__ float fast_rcp(float x) { return __builtin_amdgcn_rcpf(x); }
__device__ __forceinline__ float sigm(float x) { return fast_rcp(1.0f + __expf(-x)); }

// DPP shifted copy with 0-fill (bound_ctrl=1). CTRL is a compile-time const.
template<int CTRL>
__device__ __forceinline__ float dpp_mov0(float x) {
    return __int_as_float(
        __builtin_amdgcn_update_dpp(0, __float_as_int(x), CTRL, 0xF, 0xF, true));
}

// Full 64-lane wave sum of two values, VALU-only (HW-verified in prior rounds).
__device__ __forceinline__ void wave_red2(float& a, float& b) {
    a += dpp_mov0<0x111>(a); b += dpp_mov0<0x111>(b);   // row_shr:1
    a += dpp_mov0<0x112>(a); b += dpp_mov0<0x112>(b);   // row_shr:2
    a += dpp_mov0<0x114>(a); b += dpp_mov0<0x114>(b);   // row_shr:4
    a += dpp_mov0<0x118>(a); b += dpp_mov0<0x118>(b);   // row_shr:8
    a += dpp_mov0<0x142>(a); b += dpp_mov0<0x142>(b);   // row_bcast:15
    a += dpp_mov0<0x143>(a); b += dpp_mov0<0x143>(b);   // row_bcast:31
    a = __int_as_float(__builtin_amdgcn_readlane(__float_as_int(a), 63));
    b = __int_as_float(__builtin_amdgcn_readlane(__float_as_int(b), 63));
}

// DMA global->LDS, 16 B/lane (zero VGPR cost). LDS dest wave-uniform;
// global src per-lane. Verified working in R8/R9.
typedef const __attribute__((address_space(1))) unsigned int gas_u32;
typedef __attribute__((address_space(3))) unsigned int las_u32;
__device__ __forceinline__ void gload_lds16(const void* g, void* l) {
    __builtin_amdgcn_global_load_lds((gas_u32*)g, (las_u32*)l, 16, 0, 0);
}

// Counted vmem wait: vmcnt decrements in issue order, so vmcnt(N) ==
// "all but the newest N vmem ops are complete".
#define VMWAIT(n) asm volatile("s_waitcnt vmcnt(" #n ")" ::: "memory")
#define LGKWAIT() asm volatile("s_waitcnt lgkmcnt(0)" ::: "memory")

// ---------------------------------------------------------------------------
// Pass 1 (pipelined): each wave streams 8 consecutive chunks through a
// double-buffered LDS slice. Steady state: wait vmcnt(12) -> compute chunk k
// -> issue chunk k+2 DMAs. No barriers (wave-private LDS), no in-loop stores
// (results accumulate in registers; one epilogue store pass).
// ---------------------------------------------------------------------------
__global__ __launch_bounds__(128, 1) void pass1_kernel(
    const float* __restrict__ C, const float* __restrict__ V, const float* __restrict__ W,
    const float* __restrict__ enc, const float* __restrict__ tmod, const float* __restrict__ cmod,
    float2* __restrict__ PQ,      // [NWAVE*DD]: (P,Q) per (gc,d)
    float2* __restrict__ PaQa)    // [NWAVE]:    (pa,qa) per gc
{
    __shared__ __align__(16) float lds[P13_WPB][2][3][TT * DD];  // 48 KB/block

    const int wv   = threadIdx.x >> 6;
    const int lane = threadIdx.x & 63;
    const int wid  = blockIdx.x * P13_WPB + wv;    // 0..1023
    const int gc0  = wid * KCH;                    // 8 consecutive chunks, same b
    const int b    = gc0 >> 9;
    const int ch0  = gc0 & (NCH - 1);
    const int d2   = lane << 1;

    const size_t chunk0 = ((size_t)b * SS + ch0 * TT) * DD;
    const char* Cc = (const char*)(C + chunk0);
    const char* Wc = (const char*)(W + chunk0);
    const char* Vc = (const char*)(V + chunk0);

#define P1_ISSUE(k) do { \
    LGKWAIT(); \
    const char* Cb_ = Cc + (size_t)(k) * 4096 + (size_t)lane * 16; \
    const char* Wb_ = Wc + (size_t)(k) * 4096 + (size_t)lane * 16; \
    const char* Vb_ = Vc + (size_t)(k) * 4096 + (size_t)lane * 16; \
    _Pragma("unroll") \
    for (int i = 0; i < 4; ++i) { \
        gload_lds16(Cb_ + i * 1024, &lds[wv][(k) & 1][0][i * 256]); \
        gload_lds16(Wb_ + i * 1024, &lds[wv][(k) & 1][1][i * 256]); \
        gload_lds16(Vb_ + i * 1024, &lds[wv][(k) & 1][2][i * 256]); \
    } \
} while (0)

    P1_ISSUE(0);
    P1_ISSUE(1);

    const float2 tm = *(const float2*)(tmod + d2);
    const float2 cm = *(const float2*)(cmod + d2);
    const float2 ec = *(const float2*)(enc + b * DD + d2);
    float2 ctx;
    ctx.x = sigm(ec.x * cm.x) * ec.x;
    ctx.y = sigm(ec.y * cm.y) * ec.y;

    float2 Pr[KCH], Qr[KCH];
    float paR[KCH], qaR[KCH];

#define P1_CH(k) do { \
    float2 P = make_float2(1.f, 1.f), Q = make_float2(0.f, 0.f); \
    float sdp[TT], sep[TT]; \
    _Pragma("unroll") \
    for (int t = 0; t < TT; ++t) { \
        const float2 cv = *(const float2*)&lds[wv][(k) & 1][0][t * DD + d2]; \
        const float2 wl = *(const float2*)&lds[wv][(k) & 1][1][t * DD + d2]; \
        const float2 vl = *(const float2*)&lds[wv][(k) & 1][2][t * DD + d2]; \
        float2 dec, e2, T2; \
        dec.x = sigm(wl.x * tm.x); dec.y = sigm(wl.y * tm.y); \
        e2.x = __expf(cv.x); e2.y = __expf(cv.y); \
        T2.x = e2.x * vl.x + ctx.x; \
        T2.y = e2.y * vl.y + ctx.y; \
        Q.x = dec.x * Q.x + T2.x; \
        Q.y = dec.y * Q.y + T2.y; \
        P.x *= dec.x; P.y *= dec.y; \
        sdp[t] = dec.x + dec.y; sep[t] = e2.x + e2.y; \
    } \
    _Pragma("unroll") \
    for (int t = 0; t < TT; ++t) wave_red2(sdp[t], sep[t]); \
    float pa = 1.f, qa = 0.f; \
    _Pragma("unroll") \
    for (int t = 0; t < TT; ++t) { \
        const float mt = sdp[t] * (1.0f / DD); \
        pa *= mt; qa = mt * qa + sep[t]; \
    } \
    Pr[k] = P; Qr[k] = Q; paR[k] = pa; qaR[k] = qa; \
} while (0)

    VMWAIT(12); P1_CH(0); P1_ISSUE(2);
    VMWAIT(12); P1_CH(1); P1_ISSUE(3);
    VMWAIT(12); P1_CH(2); P1_ISSUE(4);
    VMWAIT(12); P1_CH(3); P1_ISSUE(5);
    VMWAIT(12); P1_CH(4); P1_ISSUE(6);
    VMWAIT(12); P1_CH(5); P1_ISSUE(7);
    VMWAIT(12); P1_CH(6);
    VMWAIT(0);  P1_CH(7);

#undef P1_ISSUE
#undef P1_CH

#pragma unroll
    for (int k = 0; k < KCH; ++k) {
        float4 pq4;
        pq4.x = Pr[k].x; pq4.y = Qr[k].x; pq4.z = Pr[k].y; pq4.w = Qr[k].y;
        *(float4*)(PQ + (size_t)(gc0 + k) * DD + d2) = pq4;
    }
    if (lane == 0) {
#pragma unroll
        for (int k = 0; k < KCH; ++k) PaQa[gc0 + k] = make_float2(paR[k], qaR[k]);
    }
}

// ---------------------------------------------------------------------------
// Pass 2: barrier-free wave-parallel scan (verified in R9, unchanged).
// ---------------------------------------------------------------------------
__global__ __launch_bounds__(256, 4) void pass2_kernel(
    const float2* __restrict__ PQ, const float2* __restrict__ PaQa,
    float* __restrict__ bst0, float* __restrict__ a0)
{
    const int wv   = threadIdx.x >> 6;
    const int lane = threadIdx.x & 63;
    const int wid  = blockIdx.x * 4 + wv;          // 0..2063

    if (wid < BB * DD) {
        const int b = wid >> 7;
        const int d = wid & (DD - 1);
        const int ch0 = lane * 8;
        const size_t base = ((size_t)b * NCH + ch0) * DD + d;

        float2 A[8];
#pragma unroll
        for (int i = 0; i < 8; ++i) A[i] = PQ[base + (size_t)i * DD];

        float p = 1.f, q = 0.f;
#pragma unroll
        for (int i = 0; i < 8; ++i) { q = A[i].x * q + A[i].y; p = A[i].x * p; }

#pragma unroll
        for (int dl = 1; dl < 64; dl <<= 1) {
            float ps = __shfl_up(p, dl);
            float qs = __shfl_up(q, dl);
            ps = (lane >= dl) ? ps : 1.f;
            qs = (lane >= dl) ? qs : 0.f;
            q = p * qs + q;
            p = p * ps;
        }

        float x = __shfl_up(q, 1);
        x = (lane >= 1) ? x : 0.f;
#pragma unroll
        for (int i = 0; i < 8; ++i) {
            bst0[base + (size_t)i * DD] = x;
            x = A[i].x * x + A[i].y;
        }
    } else if (wid < BB * DD + BB) {
        const int b = wid - BB * DD;
        const int ch0 = lane * 8;

        float2 A[8];
#pragma unroll
        for (int i = 0; i < 8; ++i) A[i] = PaQa[b * NCH + ch0 + i];

        float p = 1.f, q = 0.f;
#pragma unroll
        for (int i = 0; i < 8; ++i) { q = A[i].x * q + A[i].y; p = A[i].x * p; }

#pragma unroll
        for (int dl = 1; dl < 64; dl <<= 1) {
            float ps = __shfl_up(p, dl);
            float qs = __shfl_up(q, dl);
            ps = (lane >= dl) ? ps : 1.f;
            qs = (lane >= dl) ? qs : 0.f;
            q = p * qs + q;
            p = p * ps;
        }

        float x = __shfl_up(q, 1);
        x = (lane >= 1) ? x : 0.f;
#pragma unroll
        for (int i = 0; i < 8; ++i) {
            a0[b * NCH + ch0 + i] = x;
            x = A[i].x * x + A[i].y;
        }
    }
}

// ---------------------------------------------------------------------------
// Pass 3 (pipelined): same double-buffered LDS stream; recompute dec/T from
// C,W,V (L3-warm), replay from entry states, fused LayerNorm. In-loop out
// stores are accounted in the counted waits (final wait = vmcnt(8)).
// ---------------------------------------------------------------------------
__global__ __launch_bounds__(128, 1) void pass3_kernel(
    const float* __restrict__ C, const float* __restrict__ V, const float* __restrict__ W,
    const float* __restrict__ enc, const float* __restrict__ tmod, const float* __restrict__ cmod,
    const float* __restrict__ lnw, const float* __restrict__ lnb,
    const float* __restrict__ bst0, const float* __restrict__ a0,
    float* __restrict__ out)
{
    __shared__ __align__(16) float lds[P13_WPB][2][3][TT * DD];  // 48 KB/block

    const int wv   = threadIdx.x >> 6;
    const int lane = threadIdx.x & 63;
    const int wid  = blockIdx.x * P13_WPB + wv;
    const int gc0  = wid * KCH;
    const int b    = gc0 >> 9;
    const int ch0  = gc0 & (NCH - 1);
    const int d2   = lane << 1;

    const size_t chunk0 = ((size_t)b * SS + ch0 * TT) * DD;
    const char* Cc = (const char*)(C + chunk0);
    const char* Wc = (const char*)(W + chunk0);
    const char* Vc = (const char*)(V + chunk0);

    // preload entry states + params (oldest vmem ops; drained by first wait)
    float2 bstR[KCH]; float a0R[KCH];
#pragma unroll
    for (int k = 0; k < KCH; ++k) {
        bstR[k] = *(const float2*)(bst0 + (size_t)(gc0 + k) * DD + d2);
        a0R[k]  = a0[gc0 + k];
    }
    const float2 tm = *(const float2*)(tmod + d2);
    const float2 cm = *(const float2*)(cmod + d2);
    const float2 ec = *(const float2*)(enc + b * DD + d2);
    const float2 gw = *(const float2*)(lnw + d2);
    const float2 gb = *(const float2*)(lnb + d2);

#define P3_ISSUE(k) do { \
    LGKWAIT(); \
    const char* Cb_ = Cc + (size_t)(k) * 4096 + (size_t)lane * 16; \
    const char* Wb_ = Wc + (size_t)(k) * 4096 + (size_t)lane * 16; \
    const char* Vb_ = Vc + (size_t)(k) * 4096 + (size_t)lane * 16; \
    _Pragma("unroll") \
    for (int i = 0; i < 4; ++i) { \
        gload_lds16(Cb_ + i * 1024, &lds[wv][(k) & 1][0][i * 256]); \
        gload_lds16(Wb_ + i * 1024, &lds[wv][(k) & 1][1][i * 256]); \
        gload_lds16(Vb_ + i * 1024, &lds[wv][(k) & 1][2][i * 256]); \
    } \
} while (0)

    P3_ISSUE(0);
    P3_ISSUE(1);

    float2 ctx;
    ctx.x = sigm(ec.x * cm.x) * ec.x;
    ctx.y = sigm(ec.y * cm.y) * ec.y;

#define P3_CH(k) do { \
    float sdp[TT], sep[TT]; \
    _Pragma("unroll") \
    for (int t = 0; t < TT; ++t) { \
        const float2 cv = *(const float2*)&lds[wv][(k) & 1][0][t * DD + d2]; \
        const float2 wl = *(const float2*)&lds[wv][(k) & 1][1][t * DD + d2]; \
        sdp[t] = sigm(wl.x * tm.x) + sigm(wl.y * tm.y); \
        sep[t] = __expf(cv.x) + __expf(cv.y); \
    } \
    _Pragma("unroll") \
    for (int t = 0; t < TT; ++t) wave_red2(sdp[t], sep[t]); \
    float a = a0R[k]; \
    float2 bst = bstR[k]; \
    float2 o[TT]; float s1p[TT], s2p[TT]; \
    _Pragma("unroll") \
    for (int t = 0; t < TT; ++t) { \
        const float2 cv = *(const float2*)&lds[wv][(k) & 1][0][t * DD + d2]; \
        const float2 wl = *(const float2*)&lds[wv][(k) & 1][1][t * DD + d2]; \
        const float2 vl = *(const float2*)&lds[wv][(k) & 1][2][t * DD + d2]; \
        float2 dec, e2, T2; \
        dec.x = sigm(wl.x * tm.x); dec.y = sigm(wl.y * tm.y); \
        e2.x = __expf(cv.x); e2.y = __expf(cv.y); \
        T2.x = e2.x * vl.x + ctx.x; \
        T2.y = e2.y * vl.y + ctx.y; \
        const float mt = sdp[t] * (1.0f / DD); \
        a = mt * a + sep[t]; \
        bst.x = dec.x * bst.x + T2.x; \
        bst.y = dec.y * bst.y + T2.y; \
        const float inva = fast_rcp(a + REC_EPS); \
        o[t].x = bst.x * inva; o[t].y = bst.y * inva; \
        s1p[t] = o[t].x + o[t].y; \
        s2p[t] = o[t].x * o[t].x + o[t].y * o[t].y; \
    } \
    _Pragma("unroll") \
    for (int t = 0; t < TT; ++t) wave_red2(s1p[t], s2p[t]); \
    float2* Op = (float2*)(out + chunk0 + (size_t)(k) * TT * DD + d2); \
    _Pragma("unroll") \
    for (int t = 0; t < TT; ++t) { \
        const float mu  = s1p[t] * (1.0f / DD); \
        const float var = s2p[t] * (1.0f / DD) - mu * mu; \
        const float rs  = rsqrtf(var + LN_EPS); \
        float2 r; \
        r.x = (o[t].x - mu) * rs * gw.x + gb.x; \
        r.y = (o[t].y - mu) * rs * gw.y + gb.y; \
        Op[t * (DD / 2)] = r; \
    } \
} while (0)

    VMWAIT(12); P3_CH(0); P3_ISSUE(2);
    VMWAIT(12); P3_CH(1); P3_ISSUE(3);
    VMWAIT(12); P3_CH(2); P3_ISSUE(4);
    VMWAIT(12); P3_CH(3); P3_ISSUE(5);
    VMWAIT(12); P3_CH(4); P3_ISSUE(6);
    VMWAIT(12); P3_CH(5); P3_ISSUE(7);
    VMWAIT(12); P3_CH(6);
    VMWAIT(8);  P3_CH(7);

#undef P3_ISSUE
#undef P3_CH
}

extern "C" void kernel_launch(void* const* d_in, const int* in_sizes, int n_in,
                              void* d_out, int out_size, void* d_ws, size_t ws_size,
                              hipStream_t stream)
{
    const float* C    = (const float*)d_in[0];
    const float* V    = (const float*)d_in[1];
    const float* W    = (const float*)d_in[2];
    const float* enc  = (const float*)d_in[3];
    const float* tmod = (const float*)d_in[4];
    const float* cmod = (const float*)d_in[5];
    const float* lnw  = (const float*)d_in[6];
    const float* lnb  = (const float*)d_in[7];
    float* out = (float*)d_out;

    // Workspace: ~12.7 MB
    float2* PQ   = (float2*)d_ws;                       // NWAVE*DD float2
    float2* PaQa = PQ + (size_t)NWAVE * DD;             // NWAVE float2
    float*  bst0 = (float*)(PaQa + NWAVE);              // NWAVE*DD floats
    float*  a0   = bst0 + (size_t)NWAVE * DD;           // NWAVE floats

    pass1_kernel<<<P13_NBLK, 128, 0, stream>>>(C, V, W, enc, tmod, cmod, PQ, PaQa);
    pass2_kernel<<<(BB * DD + BB) / 4, 256, 0, stream>>>(PQ, PaQa, bst0, a0);
    pass3_kernel<<<P13_NBLK, 128, 0, stream>>>(C, V, W, enc, tmod, cmod, lnw, lnb,
                                               bst0, a0, out);
}

// Round 11
// 174.530 us; speedup vs baseline: 1.0305x; 1.0305x over previous
//
#include <hip/hip_runtime.h>

// Problem constants (match reference: B=16, S=4096, D=128)
#define BB   16
#define SS   4096
#define DD   128
#define NCH  512            // chunks per batch
#define TT   (SS / NCH)     // 8 steps per chunk
#define WPB  4              // waves (=chunks) per block
#define NTHR 256
#define NWAVE (BB * NCH)    // 8192 chunks

#define LN_EPS  1e-5f
#define REC_EPS 1e-8f

__device__ __forceinline__ float fast_rcp(float x) { return __builtin_amdgcn_rcpf(x); }
__device__ __forceinline__ float sigm(float x) { return fast_rcp(1.0f + __expf(-x)); }

// pack two floats as bf16 pair: lo16 = a, hi16 = b (round-half-up in magnitude)
__device__ __forceinline__ unsigned pack2(float a, float b) {
    unsigned ua = (__float_as_uint(a) + 0x8000u) >> 16;
    unsigned ub = (__float_as_uint(b) + 0x8000u) & 0xFFFF0000u;
    return ub | ua;
}
__device__ __forceinline__ float up_lo(unsigned u) { return __uint_as_float(u << 16); }
__device__ __forceinline__ float up_hi(unsigned u) { return __uint_as_float(u & 0xFFFF0000u); }

// DPP shifted copy with 0-fill (bound_ctrl=1). CTRL is a compile-time const.
template<int CTRL>
__device__ __forceinline__ float dpp_mov0(float x) {
    return __int_as_float(
        __builtin_amdgcn_update_dpp(0, __float_as_int(x), CTRL, 0xF, 0xF, true));
}

// Full 64-lane wave sum of two values, VALU-only (HW-verified in prior rounds).
__device__ __forceinline__ void wave_red2(float& a, float& b) {
    a += dpp_mov0<0x111>(a); b += dpp_mov0<0x111>(b);   // row_shr:1
    a += dpp_mov0<0x112>(a); b += dpp_mov0<0x112>(b);   // row_shr:2
    a += dpp_mov0<0x114>(a); b += dpp_mov0<0x114>(b);   // row_shr:4
    a += dpp_mov0<0x118>(a); b += dpp_mov0<0x118>(b);   // row_shr:8
    a += dpp_mov0<0x142>(a); b += dpp_mov0<0x142>(b);   // row_bcast:15
    a += dpp_mov0<0x143>(a); b += dpp_mov0<0x143>(b);   // row_bcast:31
    a = __int_as_float(__builtin_amdgcn_readlane(__float_as_int(a), 63));
    b = __int_as_float(__builtin_amdgcn_readlane(__float_as_int(b), 63));
}

// Compiler memory barrier: loads above cannot sink below.
#define LOAD_FENCE() asm volatile("" ::: "memory")

// ---------------------------------------------------------------------------
// Pass 1: EXACT R2-measured kernel (40.0 us, VGPR 40, occ 39%). Staged chunk
// loads, per-lane-only step loop, batched wave reductions, quantized P/Q.
// ---------------------------------------------------------------------------
__global__ __launch_bounds__(NTHR, 4) void pass1_kernel(
    const float* __restrict__ C, const float* __restrict__ V, const float* __restrict__ W,
    const float* __restrict__ enc, const float* __restrict__ tmod, const float* __restrict__ cmod,
    unsigned* __restrict__ DTb,
    float* __restrict__ Pbuf, float* __restrict__ Qbuf,
    float* __restrict__ PaBuf, float* __restrict__ QaBuf,
    float2* __restrict__ MEbuf)
{
    const int wv   = threadIdx.x >> 6;
    const int lane = threadIdx.x & 63;
    const int gc   = blockIdx.x * WPB + wv;        // global chunk id = b*NCH + ch
    const int b    = gc >> 9;                      // / NCH (512)
    const int ch   = gc & (NCH - 1);
    const int d2   = lane << 1;

    const int t0 = ch * TT;
    const size_t base = ((size_t)b * SS + t0) * DD + d2;
    const float2* Cp = (const float2*)(C + base);
    const float2* Vp = (const float2*)(V + base);
    const float2* Wp = (const float2*)(W + base);
    uint2* DTp = (uint2*)(DTb + base);

    const float2 tm = *(const float2*)(tmod + d2);
    const float2 cm = *(const float2*)(cmod + d2);
    const float2 ec = *(const float2*)(enc + b * DD + d2);

    // ---- staged bulk load: 24 independent loads, all in flight ----
    float2 cR[TT], wR[TT], vR[TT];
#pragma unroll
    for (int t = 0; t < TT; ++t) {
        cR[t] = Cp[t * (DD / 2)];
        wR[t] = Wp[t * (DD / 2)];
        vR[t] = Vp[t * (DD / 2)];
    }
    LOAD_FENCE();

    float2 ctx;
    ctx.x = sigm(ec.x * cm.x) * ec.x;
    ctx.y = sigm(ec.y * cm.y) * ec.y;

    float2 P = make_float2(1.f, 1.f);
    float2 Q = make_float2(0.f, 0.f);
    float sdp[TT], sep[TT];            // per-lane partials, reduced later

#pragma unroll
    for (int t = 0; t < TT; ++t) {
        float2 dec, e2, T2; uint2 u;
        dec.x = sigm(wR[t].x * tm.x); dec.y = sigm(wR[t].y * tm.y);
        e2.x = __expf(cR[t].x); e2.y = __expf(cR[t].y);
        T2.x = e2.x * vR[t].x + ctx.x;
        T2.y = e2.y * vR[t].y + ctx.y;

        u.x = pack2(dec.x, T2.x); u.y = pack2(dec.y, T2.y);
        DTp[t * (DD / 2)] = u;

        // quantized values for the scan (exact match with pass3 replay)
        const float dqx = up_lo(u.x), dqy = up_lo(u.y);
        const float tqx = up_hi(u.x), tqy = up_hi(u.y);
        Q.x = dqx * Q.x + tqx;
        Q.y = dqy * Q.y + tqy;
        P.x *= dqx; P.y *= dqy;

        sdp[t] = dec.x + dec.y;
        sep[t] = e2.x + e2.y;
    }

    // batched reductions: TT independent trees -> 2*TT-wide ILP
#pragma unroll
    for (int t = 0; t < TT; ++t) wave_red2(sdp[t], sep[t]);

    float pa = 1.f, qa = 0.f;
    float mk = 0.f, ek = 0.f;
#pragma unroll
    for (int t = 0; t < TT; ++t) {
        const float mt = sdp[t] * (1.0f / DD);
        pa *= mt;
        qa = mt * qa + sep[t];
        if (lane == t) { mk = mt; ek = sep[t]; }   // capture, store once at end
    }

    *(float2*)(Pbuf + (size_t)gc * DD + d2) = P;
    *(float2*)(Qbuf + (size_t)gc * DD + d2) = Q;
    if (lane < TT) MEbuf[(size_t)b * SS + t0 + lane] = make_float2(mk, ek);
    if (lane == 0) { PaBuf[gc] = pa; QaBuf[gc] = qa; }
}

// ---------------------------------------------------------------------------
// Pass 2: barrier-free wave-parallel scan (verified R9/R10). One wave per
// (b,d): lane-serial composite of 8 contiguous chunks, 6-round shfl_up
// affine scan, replay-write entries. 16 extra waves do the scalar a-scan.
// No LDS, no __syncthreads, 516 blocks (vs old 128-block / 32-barrier scan).
// ---------------------------------------------------------------------------
__global__ __launch_bounds__(256, 4) void pass2_kernel(
    const float* __restrict__ Pbuf, const float* __restrict__ Qbuf,
    const float* __restrict__ PaBuf, const float* __restrict__ QaBuf,
    float* __restrict__ bst0, float* __restrict__ a0)
{
    const int wv   = threadIdx.x >> 6;
    const int lane = threadIdx.x & 63;
    const int wid  = blockIdx.x * 4 + wv;          // 0..2063

    if (wid < BB * DD) {
        // ---- (b,d)-wave: scan 512 chunk affines ----
        const int b = wid >> 7;
        const int d = wid & (DD - 1);
        const int ch0 = lane * 8;                  // 8 contiguous chunks/lane
        const size_t base = ((size_t)b * NCH + ch0) * DD + d;

        float Ap[8], Aq[8];
#pragma unroll
        for (int i = 0; i < 8; ++i) {
            Ap[i] = Pbuf[base + (size_t)i * DD];
            Aq[i] = Qbuf[base + (size_t)i * DD];
        }

        // lane-serial composite (chunk order)
        float p = 1.f, q = 0.f;
#pragma unroll
        for (int i = 0; i < 8; ++i) { q = Ap[i] * q + Aq[i]; p = Ap[i] * p; }

        // wave inclusive scan of affine pairs (identity-fill via lane guard)
#pragma unroll
        for (int dl = 1; dl < 64; dl <<= 1) {
            float ps = __shfl_up(p, dl);
            float qs = __shfl_up(q, dl);
            ps = (lane >= dl) ? ps : 1.f;
            qs = (lane >= dl) ? qs : 0.f;
            q = p * qs + q;        // compose: earlier segment applied first
            p = p * ps;
        }

        // exclusive entry value (init state 0) = inclusive[lane-1].q
        float x = __shfl_up(q, 1);
        x = (lane >= 1) ? x : 0.f;

        // replay: write entry per chunk
#pragma unroll
        for (int i = 0; i < 8; ++i) {
            bst0[base + (size_t)i * DD] = x;
            x = Ap[i] * x + Aq[i];
        }
    } else if (wid < BB * DD + BB) {
        // ---- a-scan wave: one per batch ----
        const int b = wid - BB * DD;
        const int ch0 = lane * 8;

        float Ap[8], Aq[8];
#pragma unroll
        for (int i = 0; i < 8; ++i) {
            Ap[i] = PaBuf[b * NCH + ch0 + i];
            Aq[i] = QaBuf[b * NCH + ch0 + i];
        }

        float p = 1.f, q = 0.f;
#pragma unroll
        for (int i = 0; i < 8; ++i) { q = Ap[i] * q + Aq[i]; p = Ap[i] * p; }

#pragma unroll
        for (int dl = 1; dl < 64; dl <<= 1) {
            float ps = __shfl_up(p, dl);
            float qs = __shfl_up(q, dl);
            ps = (lane >= dl) ? ps : 1.f;
            qs = (lane >= dl) ? qs : 0.f;
            q = p * qs + q;
            p = p * ps;
        }

        float x = __shfl_up(q, 1);
        x = (lane >= 1) ? x : 0.f;
#pragma unroll
        for (int i = 0; i < 8; ++i) {
            a0[b * NCH + ch0 + i] = x;
            x = Ap[i] * x + Aq[i];
        }
    }
}

// ---------------------------------------------------------------------------
// Pass 3: EXACT R2-measured kernel. Staged side-band loads, per-lane replay,
// batched LN reductions, fused LayerNorm.
// ---------------------------------------------------------------------------
__global__ __launch_bounds__(NTHR, 4) void pass3_kernel(
    const unsigned* __restrict__ DTb,
    const float* __restrict__ lnw, const float* __restrict__ lnb,
    const float* __restrict__ bst0, const float* __restrict__ a0,
    const float2* __restrict__ MEbuf,
    float* __restrict__ out)
{
    const int wv   = threadIdx.x >> 6;
    const int lane = threadIdx.x & 63;
    const int gc   = blockIdx.x * WPB + wv;
    const int b    = gc >> 9;
    const int ch   = gc & (NCH - 1);
    const int d2   = lane << 1;

    const int t0 = ch * TT;
    const size_t base = ((size_t)b * SS + t0) * DD + d2;
    const uint2* DTp = (const uint2*)(DTb + base);
    float2* Op = (float2*)(out + base);

    // ---- staged bulk load: side-band + state, all in flight ----
    uint2 dtR[TT];
#pragma unroll
    for (int t = 0; t < TT; ++t) dtR[t] = DTp[t * (DD / 2)];
    const float2 me = MEbuf[(size_t)b * SS + t0 + (lane & (TT - 1))];
    float2 bst = *(const float2*)(bst0 + (size_t)gc * DD + d2);
    const float a_in = a0[gc];
    const float2 gw = *(const float2*)(lnw + d2);
    const float2 gb = *(const float2*)(lnb + d2);
    LOAD_FENCE();

    // recurrence + o values: per-lane only, full ILP
    float a = a_in;
    float2 o[TT];
    float s1p[TT], s2p[TT];
#pragma unroll
    for (int t = 0; t < TT; ++t) {
        const float mt = __int_as_float(__builtin_amdgcn_readlane(__float_as_int(me.x), t));
        const float et = __int_as_float(__builtin_amdgcn_readlane(__float_as_int(me.y), t));

        a = mt * a + et;
        bst.x = up_lo(dtR[t].x) * bst.x + up_hi(dtR[t].x);
        bst.y = up_lo(dtR[t].y) * bst.y + up_hi(dtR[t].y);

        const float inva = fast_rcp(a + REC_EPS);
        o[t].x = bst.x * inva; o[t].y = bst.y * inva;
        s1p[t] = o[t].x + o[t].y;
        s2p[t] = o[t].x * o[t].x + o[t].y * o[t].y;
    }

    // batched LN reductions: TT independent trees -> 2*TT-wide ILP
#pragma unroll
    for (int t = 0; t < TT; ++t) wave_red2(s1p[t], s2p[t]);

#pragma unroll
    for (int t = 0; t < TT; ++t) {
        const float mu  = s1p[t] * (1.0f / DD);
        const float var = s2p[t] * (1.0f / DD) - mu * mu;
        const float rs  = rsqrtf(var + LN_EPS);
        float2 r;
        r.x = (o[t].x - mu) * rs * gw.x + gb.x;
        r.y = (o[t].y - mu) * rs * gw.y + gb.y;
        Op[t * (DD / 2)] = r;
    }
}

extern "C" void kernel_launch(void* const* d_in, const int* in_sizes, int n_in,
                              void* d_out, int out_size, void* d_ws, size_t ws_size,
                              hipStream_t stream)
{
    const float* C    = (const float*)d_in[0];
    const float* V    = (const float*)d_in[1];
    const float* W    = (const float*)d_in[2];
    const float* enc  = (const float*)d_in[3];
    const float* tmod = (const float*)d_in[4];
    const float* cmod = (const float*)d_in[5];
    const float* lnw  = (const float*)d_in[6];
    const float* lnb  = (const float*)d_in[7];
    float* out = (float*)d_out;

    // Workspace layout: DT side-band (33.5 MB) + scan buffers (~13 MB)
    float* ws    = (float*)d_ws;
    unsigned* DTbuf = (unsigned*)ws;                      // BB*SS*DD uints
    float* Pbuf  = ws    + (size_t)BB * SS * DD;          // BB*NCH*DD
    float* Qbuf  = Pbuf  + (size_t)BB * NCH * DD;
    float* bst0  = Qbuf  + (size_t)BB * NCH * DD;
    float2* MEbuf = (float2*)(bst0 + (size_t)BB * NCH * DD);  // BB*SS float2
    float* PaBuf = (float*)(MEbuf + (size_t)BB * SS);         // BB*NCH
    float* QaBuf = PaBuf + (size_t)BB * NCH;
    float* a0Buf = QaBuf + (size_t)BB * NCH;

    const int nblk = BB * NCH / WPB;   // 2048
    pass1_kernel<<<nblk, NTHR, 0, stream>>>(C, V, W, enc, tmod, cmod, DTbuf,
                                            Pbuf, Qbuf, PaBuf, QaBuf, MEbuf);
    pass2_kernel<<<(BB * DD + BB + 3) / 4, 256, 0, stream>>>(Pbuf, Qbuf, PaBuf, QaBuf,
                                                             bst0, a0Buf);
    pass3_kernel<<<nblk, NTHR, 0, stream>>>(DTbuf, lnw, lnb,
                                            bst0, a0Buf, MEbuf, out);
}

// Round 12
// 159.182 us; speedup vs baseline: 1.1298x; 1.0964x over previous
//
#include <hip/hip_runtime.h>

// Problem constants (match reference: B=16, S=4096, D=128)
#define BB   16
#define SS   4096
#define DD   128
#define NCH  512            // chunks per batch
#define TT   (SS / NCH)     // 8 steps per chunk
#define WPB  4              // waves (=chunks) per block
#define NTHR 256

// pass2 two-level scan geometry
#define DTILE 16            // d's per pass2 block
#define SUBS  16            // sub-ranges per (b,d)
#define CPS   (NCH / SUBS)  // 32 chunks per sub-range

#define LN_EPS  1e-5f
#define REC_EPS 1e-8f

__device__ __forceinline__ float fast_rcp(float x) { return __builtin_amdgcn_rcpf(x); }
__device__ __forceinline__ float sigm(float x) { return fast_rcp(1.0f + __expf(-x)); }

// pack two floats as bf16 pair: lo16 = a, hi16 = b (round-half-up in magnitude)
__device__ __forceinline__ unsigned pack2(float a, float b) {
    unsigned ua = (__float_as_uint(a) + 0x8000u) >> 16;
    unsigned ub = (__float_as_uint(b) + 0x8000u) & 0xFFFF0000u;
    return ub | ua;
}
__device__ __forceinline__ float up_lo(unsigned u) { return __uint_as_float(u << 16); }
__device__ __forceinline__ float up_hi(unsigned u) { return __uint_as_float(u & 0xFFFF0000u); }

// DPP shifted copy with 0-fill (bound_ctrl=1). CTRL is a compile-time const.
template<int CTRL>
__device__ __forceinline__ float dpp_mov0(float x) {
    return __int_as_float(
        __builtin_amdgcn_update_dpp(0, __float_as_int(x), CTRL, 0xF, 0xF, true));
}

// Full 64-lane wave sum of two values, VALU-only (verified on HW in prior rounds).
__device__ __forceinline__ void wave_red2(float& a, float& b) {
    a += dpp_mov0<0x111>(a); b += dpp_mov0<0x111>(b);   // row_shr:1
    a += dpp_mov0<0x112>(a); b += dpp_mov0<0x112>(b);   // row_shr:2
    a += dpp_mov0<0x114>(a); b += dpp_mov0<0x114>(b);   // row_shr:4
    a += dpp_mov0<0x118>(a); b += dpp_mov0<0x118>(b);   // row_shr:8
    a += dpp_mov0<0x142>(a); b += dpp_mov0<0x142>(b);   // row_bcast:15
    a += dpp_mov0<0x143>(a); b += dpp_mov0<0x143>(b);   // row_bcast:31
    a = __int_as_float(__builtin_amdgcn_readlane(__float_as_int(a), 63));
    b = __int_as_float(__builtin_amdgcn_readlane(__float_as_int(b), 63));
}

// Compiler memory barrier: loads above cannot sink below.
#define LOAD_FENCE() asm volatile("" ::: "memory")

// ---------------------------------------------------------------------------
// Pass 1: stage the chunk (24 loads in flight), compute TT steps from
// registers with ONLY per-lane work in the loop; batch all 2*TT wave
// reductions at the end; then the cheap scalar a-chain. P/Q computed from
// QUANTIZED values so pass3's replay matches the scan exactly.
// (R2-measured: 40.0 us, VGPR 40, occ 39%.)
// ---------------------------------------------------------------------------
__global__ __launch_bounds__(NTHR, 4) void pass1_kernel(
    const float* __restrict__ C, const float* __restrict__ V, const float* __restrict__ W,
    const float* __restrict__ enc, const float* __restrict__ tmod, const float* __restrict__ cmod,
    unsigned* __restrict__ DTb,
    float* __restrict__ Pbuf, float* __restrict__ Qbuf,
    float* __restrict__ PaBuf, float* __restrict__ QaBuf,
    float2* __restrict__ MEbuf)
{
    const int wv   = threadIdx.x >> 6;
    const int lane = threadIdx.x & 63;
    const int gc   = blockIdx.x * WPB + wv;        // global chunk id = b*NCH + ch
    const int b    = gc >> 9;                      // / NCH (512)
    const int ch   = gc & (NCH - 1);
    const int d2   = lane << 1;

    const int t0 = ch * TT;
    const size_t base = ((size_t)b * SS + t0) * DD + d2;
    const float2* Cp = (const float2*)(C + base);
    const float2* Vp = (const float2*)(V + base);
    const float2* Wp = (const float2*)(W + base);
    uint2* DTp = (uint2*)(DTb + base);

    const float2 tm = *(const float2*)(tmod + d2);
    const float2 cm = *(const float2*)(cmod + d2);
    const float2 ec = *(const float2*)(enc + b * DD + d2);

    // ---- staged bulk load: 24 independent loads, all in flight ----
    float2 cR[TT], wR[TT], vR[TT];
#pragma unroll
    for (int t = 0; t < TT; ++t) {
        cR[t] = Cp[t * (DD / 2)];
        wR[t] = Wp[t * (DD / 2)];
        vR[t] = Vp[t * (DD / 2)];
    }
    LOAD_FENCE();

    float2 ctx;
    ctx.x = sigm(ec.x * cm.x) * ec.x;
    ctx.y = sigm(ec.y * cm.y) * ec.y;

    float2 P = make_float2(1.f, 1.f);
    float2 Q = make_float2(0.f, 0.f);
    float sdp[TT], sep[TT];            // per-lane partials, reduced later

#pragma unroll
    for (int t = 0; t < TT; ++t) {
        float2 dec, e2, T2; uint2 u;
        dec.x = sigm(wR[t].x * tm.x); dec.y = sigm(wR[t].y * tm.y);
        e2.x = __expf(cR[t].x); e2.y = __expf(cR[t].y);
        T2.x = e2.x * vR[t].x + ctx.x;
        T2.y = e2.y * vR[t].y + ctx.y;

        u.x = pack2(dec.x, T2.x); u.y = pack2(dec.y, T2.y);
        DTp[t * (DD / 2)] = u;

        // quantized values for the scan (exact match with pass3 replay)
        const float dqx = up_lo(u.x), dqy = up_lo(u.y);
        const float tqx = up_hi(u.x), tqy = up_hi(u.y);
        Q.x = dqx * Q.x + tqx;
        Q.y = dqy * Q.y + tqy;
        P.x *= dqx; P.y *= dqy;

        sdp[t] = dec.x + dec.y;
        sep[t] = e2.x + e2.y;
    }

    // batched reductions: TT independent trees -> 2*TT-wide ILP
#pragma unroll
    for (int t = 0; t < TT; ++t) wave_red2(sdp[t], sep[t]);

    float pa = 1.f, qa = 0.f;
    float mk = 0.f, ek = 0.f;
#pragma unroll
    for (int t = 0; t < TT; ++t) {
        const float mt = sdp[t] * (1.0f / DD);
        pa *= mt;
        qa = mt * qa + sep[t];
        if (lane == t) { mk = mt; ek = sep[t]; }   // capture, store once at end
    }

    *(float2*)(Pbuf + (size_t)gc * DD + d2) = P;
    *(float2*)(Qbuf + (size_t)gc * DD + d2) = Q;
    if (lane < TT) MEbuf[(size_t)b * SS + t0 + lane] = make_float2(mk, ek);
    if (lane == 0) { PaBuf[gc] = pa; QaBuf[gc] = qa; }
}

// ---------------------------------------------------------------------------
// Pass 2: two-level scan of chunk transfer functions -> chunk-entry states.
// COALESCED layout: d = dt*16 + (tid&15) -> 16 consecutive threads read/write
// 16 consecutive floats (64B segments). LDS turnaround for the cross-sub
// combine. (The R9-R11 shuffle variant's 4B/lane @4KB-stride gather/scatter
// cost +18 us via cache-line amplification -- do not reintroduce.)
// ---------------------------------------------------------------------------
__global__ __launch_bounds__(256, 2) void pass2_kernel(
    const float* __restrict__ Pbuf, const float* __restrict__ Qbuf,
    const float* __restrict__ PaBuf, const float* __restrict__ QaBuf,
    float* __restrict__ bst0, float* __restrict__ a0)
{
    const int b   = blockIdx.x >> 3;
    const int dt  = blockIdx.x & 7;
    const int tid = threadIdx.x;
    const int dl  = tid & (DTILE - 1);
    const int sub = tid >> 4;
    const int d   = dt * DTILE + dl;

    __shared__ float cP[SUBS][DTILE], cQ[SUBS][DTILE], ent[SUBS][DTILE];
    __shared__ float sPa[256], sQa[256];

    // sweep 1: local composite over this thread's 32 chunks (kept in regs)
    const int ch0 = sub * CPS;
    const size_t base = ((size_t)b * NCH + ch0) * DD + d;
    float Pr[CPS], Qr[CPS];
    float p = 1.f, q = 0.f;
#pragma unroll
    for (int i = 0; i < CPS; ++i) {
        Pr[i] = Pbuf[base + (size_t)i * DD];
        Qr[i] = Qbuf[base + (size_t)i * DD];
        q = Pr[i] * q + Qr[i];
        p = Pr[i] * p;
    }
    cP[sub][dl] = p; cQ[sub][dl] = q;
    __syncthreads();

    // combine: entry state per sub-range (init state = 0)
    if (tid < DTILE) {
        float s = 0.f;
#pragma unroll
        for (int sb = 0; sb < SUBS; ++sb) {
            ent[sb][tid] = s;
            s = cP[sb][tid] * s + cQ[sb][tid];
        }
    }
    __syncthreads();

    // sweep 2: replay from entry state, write bst0
    float s = ent[sub][dl];
#pragma unroll
    for (int i = 0; i < CPS; ++i) {
        bst0[base + (size_t)i * DD] = s;
        s = Pr[i] * s + Qr[i];
    }

    // scalar a-scan over 512 chunks: pair-compose -> 256-wide Hillis-Steele
    if (dt == 0) {
        const int cbase = b * NCH;
        const float p0 = PaBuf[cbase + 2 * tid],     q0 = QaBuf[cbase + 2 * tid];
        const float p1 = PaBuf[cbase + 2 * tid + 1], q1 = QaBuf[cbase + 2 * tid + 1];
        float Pc = p1 * p0;
        float Qc = p1 * q0 + q1;
#pragma unroll
        for (int off = 1; off < 256; off <<= 1) {
            sPa[tid] = Pc; sQa[tid] = Qc;
            __syncthreads();
            if (tid >= off) {
                const float pp = sPa[tid - off], qq = sQa[tid - off];
                Qc = Pc * qq + Qc;
                Pc = Pc * pp;
            }
            __syncthreads();
        }
        sQa[tid] = Qc;               // inclusive prefix over pairs
        __syncthreads();
        const float E = (tid == 0) ? 0.f : sQa[tid - 1];   // entry before pair
        a0[cbase + 2 * tid]     = E;
        a0[cbase + 2 * tid + 1] = p0 * E + q0;
    }
}

// ---------------------------------------------------------------------------
// Pass 3: stage the (decay,T) side-band, replay recurrence per-lane (no
// cross-lane in the loop), then batch-reduce all LN sums, then finish+store.
// ---------------------------------------------------------------------------
__global__ __launch_bounds__(NTHR, 4) void pass3_kernel(
    const unsigned* __restrict__ DTb,
    const float* __restrict__ lnw, const float* __restrict__ lnb,
    const float* __restrict__ bst0, const float* __restrict__ a0,
    const float2* __restrict__ MEbuf,
    float* __restrict__ out)
{
    const int wv   = threadIdx.x >> 6;
    const int lane = threadIdx.x & 63;
    const int gc   = blockIdx.x * WPB + wv;
    const int b    = gc >> 9;
    const int ch   = gc & (NCH - 1);
    const int d2   = lane << 1;

    const int t0 = ch * TT;
    const size_t base = ((size_t)b * SS + t0) * DD + d2;
    const uint2* DTp = (const uint2*)(DTb + base);
    float2* Op = (float2*)(out + base);

    // ---- staged bulk load: side-band + state, all in flight ----
    uint2 dtR[TT];
#pragma unroll
    for (int t = 0; t < TT; ++t) dtR[t] = DTp[t * (DD / 2)];
    const float2 me = MEbuf[(size_t)b * SS + t0 + (lane & (TT - 1))];
    float2 bst = *(const float2*)(bst0 + (size_t)gc * DD + d2);
    const float a_in = a0[gc];
    const float2 gw = *(const float2*)(lnw + d2);
    const float2 gb = *(const float2*)(lnb + d2);
    LOAD_FENCE();

    // recurrence + o values: per-lane only, full ILP
    float a = a_in;
    float2 o[TT];
    float s1p[TT], s2p[TT];
#pragma unroll
    for (int t = 0; t < TT; ++t) {
        const float mt = __int_as_float(__builtin_amdgcn_readlane(__float_as_int(me.x), t));
        const float et = __int_as_float(__builtin_amdgcn_readlane(__float_as_int(me.y), t));

        a = mt * a + et;
        bst.x = up_lo(dtR[t].x) * bst.x + up_hi(dtR[t].x);
        bst.y = up_lo(dtR[t].y) * bst.y + up_hi(dtR[t].y);

        const float inva = fast_rcp(a + REC_EPS);
        o[t].x = bst.x * inva; o[t].y = bst.y * inva;
        s1p[t] = o[t].x + o[t].y;
        s2p[t] = o[t].x * o[t].x + o[t].y * o[t].y;
    }

    // batched LN reductions: TT independent trees -> 2*TT-wide ILP
#pragma unroll
    for (int t = 0; t < TT; ++t) wave_red2(s1p[t], s2p[t]);

#pragma unroll
    for (int t = 0; t < TT; ++t) {
        const float mu  = s1p[t] * (1.0f / DD);
        const float var = s2p[t] * (1.0f / DD) - mu * mu;
        const float rs  = rsqrtf(var + LN_EPS);
        float2 r;
        r.x = (o[t].x - mu) * rs * gw.x + gb.x;
        r.y = (o[t].y - mu) * rs * gw.y + gb.y;
        Op[t * (DD / 2)] = r;
    }
}

extern "C" void kernel_launch(void* const* d_in, const int* in_sizes, int n_in,
                              void* d_out, int out_size, void* d_ws, size_t ws_size,
                              hipStream_t stream)
{
    const float* C    = (const float*)d_in[0];
    const float* V    = (const float*)d_in[1];
    const float* W    = (const float*)d_in[2];
    const float* enc  = (const float*)d_in[3];
    const float* tmod = (const float*)d_in[4];
    const float* cmod = (const float*)d_in[5];
    const float* lnw  = (const float*)d_in[6];
    const float* lnb  = (const float*)d_in[7];
    float* out = (float*)d_out;

    // Workspace layout: DT side-band (33.5 MB) + scan buffers (~13 MB)
    float* ws    = (float*)d_ws;
    unsigned* DTbuf = (unsigned*)ws;                      // BB*SS*DD uints
    float* Pbuf  = ws    + (size_t)BB * SS * DD;          // BB*NCH*DD
    float* Qbuf  = Pbuf  + (size_t)BB * NCH * DD;
    float* bst0  = Qbuf  + (size_t)BB * NCH * DD;
    float2* MEbuf = (float2*)(bst0 + (size_t)BB * NCH * DD);  // BB*SS float2
    float* PaBuf = (float*)(MEbuf + (size_t)BB * SS);         // BB*NCH
    float* QaBuf = PaBuf + (size_t)BB * NCH;
    float* a0Buf = QaBuf + (size_t)BB * NCH;

    const int nblk = BB * NCH / WPB;   // 2048
    pass1_kernel<<<nblk, NTHR, 0, stream>>>(C, V, W, enc, tmod, cmod, DTbuf,
                                            Pbuf, Qbuf, PaBuf, QaBuf, MEbuf);
    pass2_kernel<<<BB * 8, 256, 0, stream>>>(Pbuf, Qbuf, PaBuf, QaBuf, bst0, a0Buf);
    pass3_kernel<<<nblk, NTHR, 0, stream>>>(DTbuf, lnw, lnb,
                                            bst0, a0Buf, MEbuf, out);
}